// Round 1
// baseline (3344.407 us; speedup 1.0000x reference)
//
#include <hip/hip_runtime.h>
#include <hip/hip_bf16.h>

#define NNODES 100000
#define NEDGES 1600000
#define IN_F 16
#define HID 128
#define NLAYERS 8
#define BN_EPS 1e-5f

// ============================ CSR build ============================

__global__ void hist_kernel(const int* __restrict__ dst, int* __restrict__ deg, int E) {
  int i = blockIdx.x * blockDim.x + threadIdx.x;
  if (i < E) atomicAdd(&deg[dst[i]], 1);
}

// 1024 items per block (256 threads x 4)
__global__ void scan1_kernel(const int* __restrict__ deg, int* __restrict__ bsum, int N) {
  __shared__ int sdata[256];
  int b = blockIdx.x, t = threadIdx.x;
  int base = b * 1024 + t * 4;
  int s = 0;
#pragma unroll
  for (int j = 0; j < 4; ++j) {
    int i = base + j;
    if (i < N) s += deg[i];
  }
  sdata[t] = s;
  __syncthreads();
  for (int off = 128; off > 0; off >>= 1) {
    if (t < off) sdata[t] += sdata[t + off];
    __syncthreads();
  }
  if (t == 0) bsum[b] = sdata[0];
}

__global__ void scan2_kernel(const int* __restrict__ bsum, int* __restrict__ boff,
                             int nb, int* __restrict__ row_ptr, int N, int E) {
  __shared__ int s[256];
  int t = threadIdx.x;
  s[t] = (t < nb) ? bsum[t] : 0;
  __syncthreads();
  for (int off = 1; off < 256; off <<= 1) {
    int v = (t >= off) ? s[t - off] : 0;
    __syncthreads();
    s[t] += v;
    __syncthreads();
  }
  boff[t] = (t == 0) ? 0 : s[t - 1];
  if (t == 0) row_ptr[N] = E;
}

__global__ void scan3_kernel(const int* __restrict__ deg, const int* __restrict__ boff,
                             int* __restrict__ row_ptr, int* __restrict__ cursor, int N) {
  __shared__ int sdata[256];
  int b = blockIdx.x, t = threadIdx.x;
  int base = b * 1024 + t * 4;
  int v[4];
  int s = 0;
#pragma unroll
  for (int j = 0; j < 4; ++j) {
    int i = base + j;
    v[j] = (i < N) ? deg[i] : 0;
    s += v[j];
  }
  sdata[t] = s;
  __syncthreads();
  for (int off = 1; off < 256; off <<= 1) {
    int u = (t >= off) ? sdata[t - off] : 0;
    __syncthreads();
    sdata[t] += u;
    __syncthreads();
  }
  int excl = boff[b] + ((t == 0) ? 0 : sdata[t - 1]);
#pragma unroll
  for (int j = 0; j < 4; ++j) {
    int i = base + j;
    if (i < N) {
      row_ptr[i] = excl;
      cursor[i] = excl;
      excl += v[j];
    }
  }
}

__global__ void fill_kernel(const int* __restrict__ src, const int* __restrict__ dst,
                            int* __restrict__ cursor, int* __restrict__ colb, int E) {
  int i = blockIdx.x * blockDim.x + threadIdx.x;
  if (i < E) {
    int d = dst[i];
    int pos = atomicAdd(&cursor[d], 1);
    colb[pos] = src[i];
  }
}

// ============================ Aggregation ============================

// layer 0: F=16, 8 threads per node (float2 each)
__global__ __launch_bounds__(256) void agg16_kernel(
    const float* __restrict__ X, const int* __restrict__ rp, const int* __restrict__ colb,
    const float* __restrict__ eps, float* __restrict__ Z, int N) {
  int g = threadIdx.x >> 3;
  int l = threadIdx.x & 7;
  int n = blockIdx.x * 32 + g;
  if (n >= N) return;
  float e = 1.0f + eps[0];
  const float2* X2 = (const float2*)X;
  float2 acc = X2[(size_t)n * 8 + l];
  acc.x *= e; acc.y *= e;
  int beg = rp[n], end = rp[n + 1];
  for (int p = beg; p < end; ++p) {
    int s = colb[p];
    float2 v = X2[(size_t)s * 8 + l];
    acc.x += v.x; acc.y += v.y;
  }
  ((float2*)Z)[(size_t)n * 8 + l] = acc;
}

// layers 1..7: F=128, one wave (64 lanes) per node, float2 per lane
__global__ __launch_bounds__(256) void agg128_kernel(
    const float* __restrict__ H, const int* __restrict__ rp, const int* __restrict__ colb,
    const float* __restrict__ eps, int layer, float* __restrict__ Z, int N) {
  int wv = threadIdx.x >> 6;
  int lane = threadIdx.x & 63;
  int n = blockIdx.x * 4 + wv;
  if (n >= N) return;
  float e = 1.0f + eps[layer];
  const float2* H2 = (const float2*)H;
  float2 acc = H2[(size_t)n * 64 + lane];
  acc.x *= e; acc.y *= e;
  int beg = rp[n], end = rp[n + 1];
  for (int p = beg; p < end; ++p) {
    int s = colb[p];
    float2 v = H2[(size_t)s * 64 + lane];
    acc.x += v.x; acc.y += v.y;
  }
  ((float2*)Z)[(size_t)n * 64 + lane] = acc;
}

// ============================ GEMM + BN-stats ============================
// C[M,128] = preop(A[M,K]) @ B[K,128] + bias, also accumulates per-column
// sum & sumsq of C into gsum/gsq (for BatchNorm over the batch axis).
// preop (if PRE): relu(pa[k]*x + pc[k]) applied to A elements on load.
template <int K, int BK, bool PRE>
__global__ __launch_bounds__(256, 3) void gemm_bn_kernel(
    const float* __restrict__ A, const float* __restrict__ B,
    const float* __restrict__ bias,
    const float* __restrict__ pa, const float* __restrict__ pc,
    float* __restrict__ C, float* __restrict__ gsum, float* __restrict__ gsq, int M) {
  __shared__ float As[64][BK + 4];
  __shared__ float Bs[BK][HID];
  __shared__ float s_sum[HID];
  __shared__ float s_sq[HID];
  const int tid = threadIdx.x;
  const int tx = tid & 15;   // 16 col-groups of 8
  const int ty = tid >> 4;   // 16 row-groups of 4
  const int block_row = blockIdx.x * 64;

  float acc[4][8];
#pragma unroll
  for (int i = 0; i < 4; ++i)
#pragma unroll
    for (int j = 0; j < 8; ++j) acc[i][j] = 0.0f;

  for (int k0 = 0; k0 < K; k0 += BK) {
    // stage A tile (64 x BK)
    constexpr int AIT = (64 * BK / 4) / 256;
#pragma unroll
    for (int it = 0; it < AIT; ++it) {
      int t = tid + it * 256;
      int row = t / (BK / 4);
      int kq = (t % (BK / 4)) * 4;
      int grow = block_row + row;
      if (grow >= M) grow = M - 1;
      float4 v = *(const float4*)(A + (size_t)grow * K + (k0 + kq));
      if constexpr (PRE) {
        int kb = k0 + kq;
        v.x = fmaxf(fmaf(pa[kb + 0], v.x, pc[kb + 0]), 0.0f);
        v.y = fmaxf(fmaf(pa[kb + 1], v.y, pc[kb + 1]), 0.0f);
        v.z = fmaxf(fmaf(pa[kb + 2], v.z, pc[kb + 2]), 0.0f);
        v.w = fmaxf(fmaf(pa[kb + 3], v.w, pc[kb + 3]), 0.0f);
      }
      *(float4*)&As[row][kq] = v;
    }
    // stage B tile (BK x 128)
    constexpr int BIT = (BK * HID / 4) / 256;
#pragma unroll
    for (int it = 0; it < BIT; ++it) {
      int t = tid + it * 256;
      int kk = t >> 5;
      int c4 = (t & 31) * 4;
      *(float4*)&Bs[kk][c4] = *(const float4*)(B + (size_t)(k0 + kk) * HID + c4);
    }
    __syncthreads();
#pragma unroll 8
    for (int kk = 0; kk < BK; ++kk) {
      float4 b0 = *(const float4*)&Bs[kk][tx * 8];
      float4 b1 = *(const float4*)&Bs[kk][tx * 8 + 4];
#pragma unroll
      for (int i = 0; i < 4; ++i) {
        float av = As[ty * 4 + i][kk];
        acc[i][0] = fmaf(av, b0.x, acc[i][0]);
        acc[i][1] = fmaf(av, b0.y, acc[i][1]);
        acc[i][2] = fmaf(av, b0.z, acc[i][2]);
        acc[i][3] = fmaf(av, b0.w, acc[i][3]);
        acc[i][4] = fmaf(av, b1.x, acc[i][4]);
        acc[i][5] = fmaf(av, b1.y, acc[i][5]);
        acc[i][6] = fmaf(av, b1.z, acc[i][6]);
        acc[i][7] = fmaf(av, b1.w, acc[i][7]);
      }
    }
    __syncthreads();
  }

  if (tid < HID) { s_sum[tid] = 0.0f; s_sq[tid] = 0.0f; }
  __syncthreads();

  float bs[8];
#pragma unroll
  for (int j = 0; j < 8; ++j) bs[j] = bias[tx * 8 + j];

  float csum[8], csq[8];
#pragma unroll
  for (int j = 0; j < 8; ++j) { csum[j] = 0.0f; csq[j] = 0.0f; }

#pragma unroll
  for (int i = 0; i < 4; ++i) {
    int grow = block_row + ty * 4 + i;
    if (grow < M) {
      float4 o0, o1;
      float y;
      y = acc[i][0] + bs[0]; o0.x = y; csum[0] += y; csq[0] += y * y;
      y = acc[i][1] + bs[1]; o0.y = y; csum[1] += y; csq[1] += y * y;
      y = acc[i][2] + bs[2]; o0.z = y; csum[2] += y; csq[2] += y * y;
      y = acc[i][3] + bs[3]; o0.w = y; csum[3] += y; csq[3] += y * y;
      y = acc[i][4] + bs[4]; o1.x = y; csum[4] += y; csq[4] += y * y;
      y = acc[i][5] + bs[5]; o1.y = y; csum[5] += y; csq[5] += y * y;
      y = acc[i][6] + bs[6]; o1.z = y; csum[6] += y; csq[6] += y * y;
      y = acc[i][7] + bs[7]; o1.w = y; csum[7] += y; csq[7] += y * y;
      *(float4*)(C + (size_t)grow * HID + tx * 8) = o0;
      *(float4*)(C + (size_t)grow * HID + tx * 8 + 4) = o1;
    }
  }
#pragma unroll
  for (int j = 0; j < 8; ++j) {
    atomicAdd(&s_sum[tx * 8 + j], csum[j]);
    atomicAdd(&s_sq[tx * 8 + j], csq[j]);
  }
  __syncthreads();
  if (tid < HID) {
    atomicAdd(&gsum[tid], s_sum[tid]);
    atomicAdd(&gsq[tid], s_sq[tid]);
  }
}

// ============================ BN param fold ============================
__global__ void bnparam_kernel(const float* __restrict__ sum, const float* __restrict__ sq,
                               const float* __restrict__ gamma, const float* __restrict__ beta,
                               float* __restrict__ a, float* __restrict__ c, float invN) {
  int i = threadIdx.x;
  float mu = sum[i] * invN;
  float var = sq[i] * invN - mu * mu;
  float s = gamma[i] * rsqrtf(var + BN_EPS);
  a[i] = s;
  c[i] = beta[i] - s * mu;
}

__global__ void initconst_kernel(float* __restrict__ a, float* __restrict__ c) {
  int i = threadIdx.x;
  a[i] = 0.25f;
  c[i] = 0.0f;
}

// ============================ finalize: h = relu(bn(y)), skip += h ====
__global__ __launch_bounds__(256) void finalize_kernel(
    const float4* __restrict__ Y4, const float* __restrict__ a, const float* __restrict__ c,
    float4* __restrict__ H4, float4* __restrict__ S4, int doSkip, int nvec) {
  int i = blockIdx.x * blockDim.x + threadIdx.x;
  if (i >= nvec) return;
  int cb = (i & 31) << 2;
  float4 y = Y4[i];
  float4 h;
  h.x = fmaxf(fmaf(a[cb + 0], y.x, c[cb + 0]), 0.0f);
  h.y = fmaxf(fmaf(a[cb + 1], y.y, c[cb + 1]), 0.0f);
  h.z = fmaxf(fmaf(a[cb + 2], y.z, c[cb + 2]), 0.0f);
  h.w = fmaxf(fmaf(a[cb + 3], y.w, c[cb + 3]), 0.0f);
  H4[i] = h;
  if (doSkip) {
    float4 s = S4[i];
    s.x += h.x; s.y += h.y; s.z += h.z; s.w += h.w;
    S4[i] = s;
  }
}

// ============================ regressor head ============================
// out[n] = sigmoid( dot(relu(a*y[n]+c), Wr2) + br2 ), one wave per node
__global__ __launch_bounds__(256) void finaldot_kernel(
    const float* __restrict__ Y, const float* __restrict__ a, const float* __restrict__ c,
    const float* __restrict__ Wr2, const float* __restrict__ br2,
    float* __restrict__ out, int N) {
  int wv = threadIdx.x >> 6;
  int lane = threadIdx.x & 63;
  int n = blockIdx.x * 4 + wv;
  if (n >= N) return;
  const float2* Y2 = (const float2*)(Y + (size_t)n * HID);
  float2 y = Y2[lane];
  int c0 = lane * 2;
  float s = fmaxf(fmaf(a[c0], y.x, c[c0]), 0.0f) * Wr2[c0] +
            fmaxf(fmaf(a[c0 + 1], y.y, c[c0 + 1]), 0.0f) * Wr2[c0 + 1];
  for (int off = 32; off > 0; off >>= 1) s += __shfl_down(s, off, 64);
  if (lane == 0) out[n] = 1.0f / (1.0f + expf(-(s + br2[0])));
}

// ============================ launch ============================
extern "C" void kernel_launch(void* const* d_in, const int* in_sizes, int n_in,
                              void* d_out, int out_size, void* d_ws, size_t ws_size,
                              hipStream_t stream) {
  const float* x     = (const float*)d_in[0];
  const int*   ei    = (const int*)d_in[1];
  const float* eps   = (const float*)d_in[2];
  const float* W1_0  = (const float*)d_in[3];
  const float* b1_0  = (const float*)d_in[4];
  const float* W1    = (const float*)d_in[5];
  const float* b1    = (const float*)d_in[6];
  const float* g_in  = (const float*)d_in[7];
  const float* be_in = (const float*)d_in[8];
  const float* W2    = (const float*)d_in[9];
  const float* b2    = (const float*)d_in[10];
  const float* g_out = (const float*)d_in[11];
  const float* be_out= (const float*)d_in[12];
  const float* Wr1   = (const float*)d_in[13];
  const float* br1   = (const float*)d_in[14];
  const float* gr    = (const float*)d_in[15];
  const float* ber   = (const float*)d_in[16];
  const float* Wr2   = (const float*)d_in[17];
  const float* br2   = (const float*)d_in[18];
  float* out = (float*)d_out;

  const int N = in_sizes[0] / IN_F;   // 100000
  const int E = in_sizes[1] / 2;      // 1600000
  const int* srcv = ei;
  const int* dstv = ei + E;

  // workspace carve (floats)
  float* H    = (float*)d_ws;
  float* Z    = H + (size_t)N * HID;
  float* SKIP = Z + (size_t)N * HID;
  int* colb    = (int*)(SKIP + (size_t)N * HID);
  int* row_ptr = colb + E;
  int* deg     = row_ptr + (N + 1);
  int* cursor  = deg + N;
  int* bsum    = cursor + N;
  int* boff    = bsum + 256;
  float* arena = (float*)(boff + 256);
  // arena slot s (s=0..17): [sum(128) | sq(128) | a(128) | c(128)]

  hipMemsetAsync(deg, 0, sizeof(int) * N, stream);
  hipMemsetAsync(SKIP, 0, sizeof(float) * (size_t)N * HID, stream);
  hipMemsetAsync(arena, 0, sizeof(float) * 18 * 512, stream);

  // CSR build (dst -> list of src)
  hist_kernel<<<(E + 255) / 256, 256, 0, stream>>>(dstv, deg, E);
  int nb = (N + 1023) / 1024;
  scan1_kernel<<<nb, 256, 0, stream>>>(deg, bsum, N);
  scan2_kernel<<<1, 256, 0, stream>>>(bsum, boff, nb, row_ptr, N, E);
  scan3_kernel<<<nb, 256, 0, stream>>>(deg, boff, row_ptr, cursor, N);
  fill_kernel<<<(E + 255) / 256, 256, 0, stream>>>(srcv, dstv, cursor, colb, E);
  initconst_kernel<<<1, HID, 0, stream>>>(arena + 17 * 512 + 256, arena + 17 * 512 + 384);

  const int gemm_grid = (N + 63) / 64;
  const float invN = 1.0f / (float)N;
  const int fin_grid = (N * HID / 4) / 256;

  // ---- layer 0 (input features = 16) ----
  agg16_kernel<<<N / 32, 256, 0, stream>>>(x, row_ptr, colb, eps, Z, N);
  {
    float* s0 = arena + 0 * 512;
    float* s1 = arena + 1 * 512;
    gemm_bn_kernel<IN_F, IN_F, false><<<gemm_grid, 256, 0, stream>>>(
        Z, W1_0, b1_0, nullptr, nullptr, H, s0, s0 + 128, N);
    bnparam_kernel<<<1, HID, 0, stream>>>(s0, s0 + 128, g_in, be_in, s0 + 256, s0 + 384, invN);
    gemm_bn_kernel<HID, 64, true><<<gemm_grid, 256, 0, stream>>>(
        H, W2, b2, s0 + 256, s0 + 384, Z, s1, s1 + 128, N);
    bnparam_kernel<<<1, HID, 0, stream>>>(s1, s1 + 128, g_out, be_out, s1 + 256, s1 + 384, invN);
    finalize_kernel<<<fin_grid, 256, 0, stream>>>(
        (const float4*)Z, s1 + 256, s1 + 384, (float4*)H, (float4*)SKIP, 0, N * HID / 4);
  }

  // ---- layers 1..7 ----
  for (int L = 1; L < NLAYERS; ++L) {
    agg128_kernel<<<N / 4, 256, 0, stream>>>(H, row_ptr, colb, eps, L, Z, N);
    float* s0 = arena + (2 * L) * 512;
    float* s1 = arena + (2 * L + 1) * 512;
    gemm_bn_kernel<HID, 64, false><<<gemm_grid, 256, 0, stream>>>(
        Z, W1 + (size_t)(L - 1) * HID * HID, b1 + (size_t)(L - 1) * HID,
        nullptr, nullptr, H, s0, s0 + 128, N);
    bnparam_kernel<<<1, HID, 0, stream>>>(s0, s0 + 128, g_in + (size_t)L * HID,
                                          be_in + (size_t)L * HID, s0 + 256, s0 + 384, invN);
    gemm_bn_kernel<HID, 64, true><<<gemm_grid, 256, 0, stream>>>(
        H, W2 + (size_t)L * HID * HID, b2 + (size_t)L * HID,
        s0 + 256, s0 + 384, Z, s1, s1 + 128, N);
    bnparam_kernel<<<1, HID, 0, stream>>>(s1, s1 + 128, g_out + (size_t)L * HID,
                                          be_out + (size_t)L * HID, s1 + 256, s1 + 384, invN);
    finalize_kernel<<<fin_grid, 256, 0, stream>>>(
        (const float4*)Z, s1 + 256, s1 + 384, (float4*)H, (float4*)SKIP, L & 1, N * HID / 4);
  }

  // ---- regressor ----
  float* sr = arena + 16 * 512;
  float* pk = arena + 17 * 512;  // const pre-op: a=0.25, c=0 (skip>=0 so relu is no-op)
  gemm_bn_kernel<HID, 64, true><<<gemm_grid, 256, 0, stream>>>(
      SKIP, Wr1, br1, pk + 256, pk + 384, H, sr, sr + 128, N);
  bnparam_kernel<<<1, HID, 0, stream>>>(sr, sr + 128, gr, ber, sr + 256, sr + 384, invN);
  finaldot_kernel<<<N / 4, 256, 0, stream>>>(H, sr + 256, sr + 384, Wr2, br2, out, N);
}

// Round 2
// 3060.313 us; speedup vs baseline: 1.0928x; 1.0928x over previous
//
#include <hip/hip_runtime.h>
#include <hip/hip_bf16.h>

#define NNODES 100000
#define NEDGES 1600000
#define IN_F 16
#define HID 128
#define NLAYERS 8
#define BN_EPS 1e-5f

// ============================ CSR build ============================

__global__ void hist_kernel(const int* __restrict__ dst, int* __restrict__ deg, int E) {
  int i = blockIdx.x * blockDim.x + threadIdx.x;
  if (i < E) atomicAdd(&deg[dst[i]], 1);
}

__global__ void scan1_kernel(const int* __restrict__ deg, int* __restrict__ bsum, int N) {
  __shared__ int sdata[256];
  int b = blockIdx.x, t = threadIdx.x;
  int base = b * 1024 + t * 4;
  int s = 0;
#pragma unroll
  for (int j = 0; j < 4; ++j) {
    int i = base + j;
    if (i < N) s += deg[i];
  }
  sdata[t] = s;
  __syncthreads();
  for (int off = 128; off > 0; off >>= 1) {
    if (t < off) sdata[t] += sdata[t + off];
    __syncthreads();
  }
  if (t == 0) bsum[b] = sdata[0];
}

__global__ void scan2_kernel(const int* __restrict__ bsum, int* __restrict__ boff,
                             int nb, int* __restrict__ row_ptr, int N, int E) {
  __shared__ int s[256];
  int t = threadIdx.x;
  s[t] = (t < nb) ? bsum[t] : 0;
  __syncthreads();
  for (int off = 1; off < 256; off <<= 1) {
    int v = (t >= off) ? s[t - off] : 0;
    __syncthreads();
    s[t] += v;
    __syncthreads();
  }
  boff[t] = (t == 0) ? 0 : s[t - 1];
  if (t == 0) row_ptr[N] = E;
}

__global__ void scan3_kernel(const int* __restrict__ deg, const int* __restrict__ boff,
                             int* __restrict__ row_ptr, int* __restrict__ cursor, int N) {
  __shared__ int sdata[256];
  int b = blockIdx.x, t = threadIdx.x;
  int base = b * 1024 + t * 4;
  int v[4];
  int s = 0;
#pragma unroll
  for (int j = 0; j < 4; ++j) {
    int i = base + j;
    v[j] = (i < N) ? deg[i] : 0;
    s += v[j];
  }
  sdata[t] = s;
  __syncthreads();
  for (int off = 1; off < 256; off <<= 1) {
    int u = (t >= off) ? sdata[t - off] : 0;
    __syncthreads();
    sdata[t] += u;
    __syncthreads();
  }
  int excl = boff[b] + ((t == 0) ? 0 : sdata[t - 1]);
#pragma unroll
  for (int j = 0; j < 4; ++j) {
    int i = base + j;
    if (i < N) {
      row_ptr[i] = excl;
      cursor[i] = excl;
      excl += v[j];
    }
  }
}

__global__ void fill_kernel(const int* __restrict__ src, const int* __restrict__ dst,
                            int* __restrict__ cursor, int* __restrict__ colb, int E) {
  int i = blockIdx.x * blockDim.x + threadIdx.x;
  if (i < E) {
    int d = dst[i];
    int pos = atomicAdd(&cursor[d], 1);
    colb[pos] = src[i];
  }
}

// ============================ Aggregation ============================

// layer 0: F=16, 8 threads per node (float2 each), reads x raw
__global__ __launch_bounds__(256) void agg16_kernel(
    const float* __restrict__ X, const int* __restrict__ rp, const int* __restrict__ colb,
    const float* __restrict__ eps, float* __restrict__ Z, int N) {
  int g = threadIdx.x >> 3;
  int l = threadIdx.x & 7;
  int n = blockIdx.x * 32 + g;
  if (n >= N) return;
  float e = 1.0f + eps[0];
  const float2* X2 = (const float2*)X;
  float2 self = X2[(size_t)n * 8 + l];
  float2 acc = make_float2(self.x * e, self.y * e);
  float2 acc2 = make_float2(0.0f, 0.0f);
  int beg = rp[n], end = rp[n + 1];
  int p = beg;
  for (; p + 4 <= end; p += 4) {
    int s0 = colb[p], s1 = colb[p + 1], s2 = colb[p + 2], s3 = colb[p + 3];
    float2 v0 = X2[(size_t)s0 * 8 + l];
    float2 v1 = X2[(size_t)s1 * 8 + l];
    float2 v2 = X2[(size_t)s2 * 8 + l];
    float2 v3 = X2[(size_t)s3 * 8 + l];
    acc.x += v0.x; acc.y += v0.y;
    acc2.x += v1.x; acc2.y += v1.y;
    acc.x += v2.x; acc.y += v2.y;
    acc2.x += v3.x; acc2.y += v3.y;
  }
  for (; p < end; ++p) {
    int s = colb[p];
    float2 v = X2[(size_t)s * 8 + l];
    acc.x += v.x; acc.y += v.y;
  }
  acc.x += acc2.x; acc.y += acc2.y;
  ((float2*)Z)[(size_t)n * 8 + l] = acc;
}

// layers 1..7: one wave per node, float2 per lane. Input Y is the PRE-BN
// output of the previous layer's gemm2; transform h=relu(a*y+c) is applied
// per gathered element (fused finalize). Optionally SKIP += h(self).
__global__ __launch_bounds__(256) void agg128_kernel(
    const float* __restrict__ Y, const float* __restrict__ av, const float* __restrict__ cv,
    const int* __restrict__ rp, const int* __restrict__ colb,
    const float* __restrict__ eps, int layer, float* __restrict__ Z,
    float* __restrict__ SKIP, int N) {
  int wv = threadIdx.x >> 6;
  int lane = threadIdx.x & 63;
  int n = blockIdx.x * 4 + wv;
  if (n >= N) return;
  float e = 1.0f + eps[layer];
  float2 a2 = ((const float2*)av)[lane];
  float2 c2 = ((const float2*)cv)[lane];
  const float2* Y2 = (const float2*)Y;
  float2 sv = Y2[(size_t)n * 64 + lane];
  float2 self;
  self.x = fmaxf(fmaf(a2.x, sv.x, c2.x), 0.0f);
  self.y = fmaxf(fmaf(a2.y, sv.y, c2.y), 0.0f);
  if (SKIP) {
    float2* S2 = (float2*)SKIP;
    float2 s = S2[(size_t)n * 64 + lane];
    s.x += self.x; s.y += self.y;
    S2[(size_t)n * 64 + lane] = s;
  }
  float2 acc = make_float2(self.x * e, self.y * e);
  float2 acc2 = make_float2(0.0f, 0.0f);
  int beg = rp[n], end = rp[n + 1];
  int p = beg;
  for (; p + 4 <= end; p += 4) {
    int s0 = colb[p], s1 = colb[p + 1], s2 = colb[p + 2], s3 = colb[p + 3];
    float2 v0 = Y2[(size_t)s0 * 64 + lane];
    float2 v1 = Y2[(size_t)s1 * 64 + lane];
    float2 v2 = Y2[(size_t)s2 * 64 + lane];
    float2 v3 = Y2[(size_t)s3 * 64 + lane];
    acc.x += fmaxf(fmaf(a2.x, v0.x, c2.x), 0.0f);
    acc.y += fmaxf(fmaf(a2.y, v0.y, c2.y), 0.0f);
    acc2.x += fmaxf(fmaf(a2.x, v1.x, c2.x), 0.0f);
    acc2.y += fmaxf(fmaf(a2.y, v1.y, c2.y), 0.0f);
    acc.x += fmaxf(fmaf(a2.x, v2.x, c2.x), 0.0f);
    acc.y += fmaxf(fmaf(a2.y, v2.y, c2.y), 0.0f);
    acc2.x += fmaxf(fmaf(a2.x, v3.x, c2.x), 0.0f);
    acc2.y += fmaxf(fmaf(a2.y, v3.y, c2.y), 0.0f);
  }
  for (; p < end; ++p) {
    int s = colb[p];
    float2 v = Y2[(size_t)s * 64 + lane];
    acc.x += fmaxf(fmaf(a2.x, v.x, c2.x), 0.0f);
    acc.y += fmaxf(fmaf(a2.y, v.y, c2.y), 0.0f);
  }
  acc.x += acc2.x; acc.y += acc2.y;
  ((float2*)Z)[(size_t)n * 64 + lane] = acc;
}

// ============================ GEMM + BN stats + BN-param fold ============
// C[M,128] = op(A)[M,K] @ B[K,128] + bias, accumulating per-column sum/sumsq.
// The LAST block to finish also folds stats into (a,c): a=gamma*rsqrt(var+eps),
// c=beta-a*mu, so no separate bnparam kernel / extra dispatch is needed.
// MODE 0: op(A)=A      MODE 1: op(A)=relu(pa*A+pc)
// MODE 2: op(A)=0.25*(A + relu(pa*A2+pc))   (regressor: skip + last layer h)
template <int K, int BK, int MODE>
__global__ __launch_bounds__(256, 3) void gemm_kernel(
    const float* __restrict__ A, const float* __restrict__ A2,
    const float* __restrict__ B, const float* __restrict__ bias,
    const float* __restrict__ pa, const float* __restrict__ pc,
    float* __restrict__ C,
    float* __restrict__ gsum, float* __restrict__ gsq,
    float* __restrict__ aout, float* __restrict__ cout, int* __restrict__ cnt,
    const float* __restrict__ gamma, const float* __restrict__ beta,
    float invN, int M, int nb) {
  __shared__ float As[BK][132];   // transposed: As[k][row], 132 keeps float4 alignment
  __shared__ float Bs[BK][128];
  __shared__ float s_sum[128];
  __shared__ float s_sq[128];
  __shared__ int s_last;
  const int tid = threadIdx.x;
  const int tx = tid & 15;   // 16 col groups of 8
  const int ty = tid >> 4;   // 16 row groups of 8
  const int brow = blockIdx.x * 128;

  float acc[8][8];
#pragma unroll
  for (int i = 0; i < 8; ++i)
#pragma unroll
    for (int j = 0; j < 8; ++j) acc[i][j] = 0.0f;

  for (int k0 = 0; k0 < K; k0 += BK) {
    // stage A (128 x BK), transposed into As[k][row]
    constexpr int AV = (128 * (BK / 4)) / 256;
#pragma unroll
    for (int it = 0; it < AV; ++it) {
      int idx = tid + it * 256;
      int row = idx / (BK / 4);
      int kq = (idx % (BK / 4)) * 4;
      int grow = brow + row;
      if (grow >= M) grow = M - 1;
      float4 v = *(const float4*)(A + (size_t)grow * K + (k0 + kq));
      if constexpr (MODE == 1) {
        int kb = k0 + kq;
        v.x = fmaxf(fmaf(pa[kb + 0], v.x, pc[kb + 0]), 0.0f);
        v.y = fmaxf(fmaf(pa[kb + 1], v.y, pc[kb + 1]), 0.0f);
        v.z = fmaxf(fmaf(pa[kb + 2], v.z, pc[kb + 2]), 0.0f);
        v.w = fmaxf(fmaf(pa[kb + 3], v.w, pc[kb + 3]), 0.0f);
      } else if constexpr (MODE == 2) {
        int kb = k0 + kq;
        float4 w = *(const float4*)(A2 + (size_t)grow * K + (k0 + kq));
        v.x = 0.25f * (v.x + fmaxf(fmaf(pa[kb + 0], w.x, pc[kb + 0]), 0.0f));
        v.y = 0.25f * (v.y + fmaxf(fmaf(pa[kb + 1], w.y, pc[kb + 1]), 0.0f));
        v.z = 0.25f * (v.z + fmaxf(fmaf(pa[kb + 2], w.z, pc[kb + 2]), 0.0f));
        v.w = 0.25f * (v.w + fmaxf(fmaf(pa[kb + 3], w.w, pc[kb + 3]), 0.0f));
      }
      As[kq + 0][row] = v.x;
      As[kq + 1][row] = v.y;
      As[kq + 2][row] = v.z;
      As[kq + 3][row] = v.w;
    }
    // stage B (BK x 128)
    constexpr int BV = (BK * 32) / 256;
#pragma unroll
    for (int it = 0; it < BV; ++it) {
      int idx = tid + it * 256;
      int kk = idx >> 5;
      int c4 = (idx & 31) * 4;
      *(float4*)&Bs[kk][c4] = *(const float4*)(B + (size_t)(k0 + kk) * 128 + c4);
    }
    __syncthreads();
#pragma unroll 8
    for (int kk = 0; kk < BK; ++kk) {
      float4 a0 = *(const float4*)&As[kk][ty * 8];
      float4 a1 = *(const float4*)&As[kk][ty * 8 + 4];
      float4 b0 = *(const float4*)&Bs[kk][tx * 8];
      float4 b1 = *(const float4*)&Bs[kk][tx * 8 + 4];
      float av[8] = {a0.x, a0.y, a0.z, a0.w, a1.x, a1.y, a1.z, a1.w};
      float bv[8] = {b0.x, b0.y, b0.z, b0.w, b1.x, b1.y, b1.z, b1.w};
#pragma unroll
      for (int i = 0; i < 8; ++i)
#pragma unroll
        for (int j = 0; j < 8; ++j) acc[i][j] = fmaf(av[i], bv[j], acc[i][j]);
    }
    __syncthreads();
  }

  if (tid < 128) { s_sum[tid] = 0.0f; s_sq[tid] = 0.0f; }
  __syncthreads();

  float bs[8];
#pragma unroll
  for (int j = 0; j < 8; ++j) bs[j] = bias[tx * 8 + j];
  float csum[8], csq[8];
#pragma unroll
  for (int j = 0; j < 8; ++j) { csum[j] = 0.0f; csq[j] = 0.0f; }

#pragma unroll
  for (int i = 0; i < 8; ++i) {
    int grow = brow + ty * 8 + i;
    if (grow < M) {
      float4 o0, o1;
      float y;
      y = acc[i][0] + bs[0]; o0.x = y; csum[0] += y; csq[0] += y * y;
      y = acc[i][1] + bs[1]; o0.y = y; csum[1] += y; csq[1] += y * y;
      y = acc[i][2] + bs[2]; o0.z = y; csum[2] += y; csq[2] += y * y;
      y = acc[i][3] + bs[3]; o0.w = y; csum[3] += y; csq[3] += y * y;
      y = acc[i][4] + bs[4]; o1.x = y; csum[4] += y; csq[4] += y * y;
      y = acc[i][5] + bs[5]; o1.y = y; csum[5] += y; csq[5] += y * y;
      y = acc[i][6] + bs[6]; o1.z = y; csum[6] += y; csq[6] += y * y;
      y = acc[i][7] + bs[7]; o1.w = y; csum[7] += y; csq[7] += y * y;
      *(float4*)(C + (size_t)grow * 128 + tx * 8) = o0;
      *(float4*)(C + (size_t)grow * 128 + tx * 8 + 4) = o1;
    }
  }
#pragma unroll
  for (int j = 0; j < 8; ++j) {
    atomicAdd(&s_sum[tx * 8 + j], csum[j]);
    atomicAdd(&s_sq[tx * 8 + j], csq[j]);
  }
  __syncthreads();
  if (tid < 128) {
    atomicAdd(&gsum[tid], s_sum[tid]);
    atomicAdd(&gsq[tid], s_sq[tid]);
  }
  // last block folds BN params
  if (tid == 0) {
    __threadfence();
    int v = __hip_atomic_fetch_add(cnt, 1, __ATOMIC_ACQ_REL, __HIP_MEMORY_SCOPE_AGENT);
    s_last = (v == nb - 1) ? 1 : 0;
  }
  __syncthreads();
  if (s_last && tid < 128) {
    float s = __hip_atomic_load(&gsum[tid], __ATOMIC_RELAXED, __HIP_MEMORY_SCOPE_AGENT);
    float q = __hip_atomic_load(&gsq[tid], __ATOMIC_RELAXED, __HIP_MEMORY_SCOPE_AGENT);
    float mu = s * invN;
    float var = q * invN - mu * mu;
    float sc = gamma[tid] * rsqrtf(var + BN_EPS);
    aout[tid] = sc;
    cout[tid] = beta[tid] - sc * mu;
  }
}

// ============================ regressor head ============================
__global__ __launch_bounds__(256) void finaldot_kernel(
    const float* __restrict__ Y, const float* __restrict__ a, const float* __restrict__ c,
    const float* __restrict__ Wr2, const float* __restrict__ br2,
    float* __restrict__ out, int N) {
  int wv = threadIdx.x >> 6;
  int lane = threadIdx.x & 63;
  int n = blockIdx.x * 4 + wv;
  if (n >= N) return;
  const float2* Y2 = (const float2*)(Y + (size_t)n * HID);
  float2 y = Y2[lane];
  int c0 = lane * 2;
  float s = fmaxf(fmaf(a[c0], y.x, c[c0]), 0.0f) * Wr2[c0] +
            fmaxf(fmaf(a[c0 + 1], y.y, c[c0 + 1]), 0.0f) * Wr2[c0 + 1];
  for (int off = 32; off > 0; off >>= 1) s += __shfl_down(s, off, 64);
  if (lane == 0) out[n] = 1.0f / (1.0f + expf(-(s + br2[0])));
}

// ============================ launch ============================
extern "C" void kernel_launch(void* const* d_in, const int* in_sizes, int n_in,
                              void* d_out, int out_size, void* d_ws, size_t ws_size,
                              hipStream_t stream) {
  const float* x     = (const float*)d_in[0];
  const int*   ei    = (const int*)d_in[1];
  const float* eps   = (const float*)d_in[2];
  const float* W1_0  = (const float*)d_in[3];
  const float* b1_0  = (const float*)d_in[4];
  const float* W1    = (const float*)d_in[5];
  const float* b1    = (const float*)d_in[6];
  const float* g_in  = (const float*)d_in[7];
  const float* be_in = (const float*)d_in[8];
  const float* W2    = (const float*)d_in[9];
  const float* b2    = (const float*)d_in[10];
  const float* g_out = (const float*)d_in[11];
  const float* be_out= (const float*)d_in[12];
  const float* Wr1   = (const float*)d_in[13];
  const float* br1   = (const float*)d_in[14];
  const float* gr    = (const float*)d_in[15];
  const float* ber   = (const float*)d_in[16];
  const float* Wr2   = (const float*)d_in[17];
  const float* br2   = (const float*)d_in[18];
  float* out = (float*)d_out;

  const int N = in_sizes[0] / IN_F;   // 100000
  const int E = in_sizes[1] / 2;      // 1600000
  const int* srcv = ei;
  const int* dstv = ei + E;

  // workspace carve
  float* BA   = (float*)d_ws;                  // big buffer A
  float* BB   = BA + (size_t)N * HID;          // big buffer B
  float* SKIP = BB + (size_t)N * HID;
  int* colb    = (int*)(SKIP + (size_t)N * HID);
  int* row_ptr = colb + E;
  int* deg     = row_ptr + (N + 1);
  int* cursor  = deg + N;
  int* bsum    = cursor + N;
  int* boff    = bsum + 256;
  float* arena = (float*)(boff + 256);
  // arena slot s (s=0..16), 640 floats each: [sum 128 | sq 128 | a 128 | c 128 | cnt]

  hipMemsetAsync(deg, 0, sizeof(int) * N, stream);
  hipMemsetAsync(SKIP, 0, sizeof(float) * (size_t)N * HID, stream);
  hipMemsetAsync(arena, 0, sizeof(float) * 17 * 640, stream);

  // CSR build (dst -> list of src)
  hist_kernel<<<(E + 255) / 256, 256, 0, stream>>>(dstv, deg, E);
  int nbs = (N + 1023) / 1024;
  scan1_kernel<<<nbs, 256, 0, stream>>>(deg, bsum, N);
  scan2_kernel<<<1, 256, 0, stream>>>(bsum, boff, nbs, row_ptr, N, E);
  scan3_kernel<<<nbs, 256, 0, stream>>>(deg, boff, row_ptr, cursor, N);
  fill_kernel<<<(E + 255) / 256, 256, 0, stream>>>(srcv, dstv, cursor, colb, E);

  const int gg = (N + 127) / 128;  // gemm grid
  const float invN = 1.0f / (float)N;
#define SLOT(s) (arena + (s) * 640)
#define SSUM(s) SLOT(s)
#define SSQ(s)  (SLOT(s) + 128)
#define SA(s)   (SLOT(s) + 256)
#define SC(s)   (SLOT(s) + 384)
#define SCNT(s) ((int*)(SLOT(s) + 512))

  // ---- layer 0 ----
  agg16_kernel<<<(N + 31) / 32, 256, 0, stream>>>(x, row_ptr, colb, eps, BA, N);
  gemm_kernel<IN_F, IN_F, 0><<<gg, 256, 0, stream>>>(
      BA, nullptr, W1_0, b1_0, nullptr, nullptr, BB,
      SSUM(0), SSQ(0), SA(0), SC(0), SCNT(0), g_in, be_in, invN, N, gg);
  gemm_kernel<HID, 32, 1><<<gg, 256, 0, stream>>>(
      BB, nullptr, W2, b2, SA(0), SC(0), BA,
      SSUM(1), SSQ(1), SA(1), SC(1), SCNT(1), g_out, be_out, invN, N, gg);
  // Y2_0 now in BA, BN params in slot 1

  // ---- layers 1..7 ----
  float* P = BA;   // Y2_prev
  float* Q = BB;   // scratch
  for (int L = 1; L < NLAYERS; ++L) {
    int sp = 2 * L - 1;          // prev outer-BN slot
    int s0 = 2 * L, s1 = 2 * L + 1;
    float* skipw = ((L - 1) & 1) ? SKIP : nullptr;  // fold h_{L-1} into SKIP for L=2,4,6
    agg128_kernel<<<(N + 3) / 4, 256, 0, stream>>>(
        P, SA(sp), SC(sp), row_ptr, colb, eps, L, Q, skipw, N);
    gemm_kernel<HID, 32, 0><<<gg, 256, 0, stream>>>(
        Q, nullptr, W1 + (size_t)(L - 1) * HID * HID, b1 + (size_t)(L - 1) * HID,
        nullptr, nullptr, P,
        SSUM(s0), SSQ(s0), SA(s0), SC(s0), SCNT(s0),
        g_in + (size_t)L * HID, be_in + (size_t)L * HID, invN, N, gg);
    gemm_kernel<HID, 32, 1><<<gg, 256, 0, stream>>>(
        P, nullptr, W2 + (size_t)L * HID * HID, b2 + (size_t)L * HID,
        SA(s0), SC(s0), Q,
        SSUM(s1), SSQ(s1), SA(s1), SC(s1), SCNT(s1),
        g_out + (size_t)L * HID, be_out + (size_t)L * HID, invN, N, gg);
    // Y2_L now in Q; swap
    float* t = P; P = Q; Q = t;
  }
  // after loop: P = Y2_7, slot 15 has its BN params

  // ---- regressor: A_eff = 0.25*(SKIP + relu(a7*Y2_7+c7)) ----
  gemm_kernel<HID, 32, 2><<<gg, 256, 0, stream>>>(
      SKIP, P, Wr1, br1, SA(15), SC(15), Q,
      SSUM(16), SSQ(16), SA(16), SC(16), SCNT(16), gr, ber, invN, N, gg);
  finaldot_kernel<<<(N + 3) / 4, 256, 0, stream>>>(Q, SA(16), SC(16), Wr2, br2, out, N);
#undef SLOT
#undef SSUM
#undef SSQ
#undef SA
#undef SC
#undef SCNT
}

// Round 4
// 2614.889 us; speedup vs baseline: 1.2790x; 1.1703x over previous
//
#include <hip/hip_runtime.h>
#include <hip/hip_bf16.h>

#define NNODES 100000
#define NEDGES 1600000
#define IN_F 16
#define HID 128
#define NLAYERS 8
#define BN_EPS 1e-5f
#define BLOBSZ 532480   // ushorts per blob half: 8192 + 16*32768

typedef __attribute__((ext_vector_type(8))) short short8;
typedef __attribute__((ext_vector_type(4))) float f32x4;
typedef unsigned short ushort_t;
typedef unsigned int uint_t;

__device__ __forceinline__ ushort_t f2bf(float f) {
  uint_t u = __builtin_bit_cast(uint_t, f);
  uint_t r = (u + 0x7fffu + ((u >> 16) & 1u)) >> 16;
  return (ushort_t)r;
}
__device__ __forceinline__ float bfl(uint_t u) {
  return __builtin_bit_cast(float, u << 16);
}

// split v = hi + lo (both bf16), |err| ~ 2^-16 rel
__device__ __forceinline__ void bsplit(float v, ushort_t& h, ushort_t& l) {
  h = f2bf(v);
  float r = v - bfl((uint_t)h);
  l = f2bf(r);
}

// ============================ CSR build ============================

__global__ void hist_kernel(const int* __restrict__ dst, int* __restrict__ deg, int E) {
  int i = blockIdx.x * blockDim.x + threadIdx.x;
  if (i < E) atomicAdd(&deg[dst[i]], 1);
}

__global__ void scan1_kernel(const int* __restrict__ deg, int* __restrict__ bsum, int N) {
  __shared__ int sdata[256];
  int b = blockIdx.x, t = threadIdx.x;
  int base = b * 1024 + t * 4;
  int s = 0;
#pragma unroll
  for (int j = 0; j < 4; ++j) {
    int i = base + j;
    if (i < N) s += deg[i];
  }
  sdata[t] = s;
  __syncthreads();
  for (int off = 128; off > 0; off >>= 1) {
    if (t < off) sdata[t] += sdata[t + off];
    __syncthreads();
  }
  if (t == 0) bsum[b] = sdata[0];
}

__global__ void scan2_kernel(const int* __restrict__ bsum, int* __restrict__ boff,
                             int nb, int* __restrict__ row_ptr, int N, int E) {
  __shared__ int s[256];
  int t = threadIdx.x;
  s[t] = (t < nb) ? bsum[t] : 0;
  __syncthreads();
  for (int off = 1; off < 256; off <<= 1) {
    int v = (t >= off) ? s[t - off] : 0;
    __syncthreads();
    s[t] += v;
    __syncthreads();
  }
  boff[t] = (t == 0) ? 0 : s[t - 1];
  if (t == 0) row_ptr[N] = E;
}

__global__ void scan3_kernel(const int* __restrict__ deg, const int* __restrict__ boff,
                             int* __restrict__ row_ptr, int* __restrict__ cursor, int N) {
  __shared__ int sdata[256];
  int b = blockIdx.x, t = threadIdx.x;
  int base = b * 1024 + t * 4;
  int v[4];
  int s = 0;
#pragma unroll
  for (int j = 0; j < 4; ++j) {
    int i = base + j;
    v[j] = (i < N) ? deg[i] : 0;
    s += v[j];
  }
  sdata[t] = s;
  __syncthreads();
  for (int off = 1; off < 256; off <<= 1) {
    int u = (t >= off) ? sdata[t - off] : 0;
    __syncthreads();
    sdata[t] += u;
    __syncthreads();
  }
  int excl = boff[b] + ((t == 0) ? 0 : sdata[t - 1]);
#pragma unroll
  for (int j = 0; j < 4; ++j) {
    int i = base + j;
    if (i < N) {
      row_ptr[i] = excl;
      cursor[i] = excl;
      excl += v[j];
    }
  }
}

__global__ void fill_kernel(const int* __restrict__ src, const int* __restrict__ dst,
                            int* __restrict__ cursor, int* __restrict__ colb, int E) {
  int i = blockIdx.x * blockDim.x + threadIdx.x;
  if (i < E) {
    int d = dst[i];
    int pos = atomicAdd(&cursor[d], 1);
    colb[pos] = src[i];
  }
}

// =================== weight pre-convert: split hi/lo MFMA-frag blobs ===================
// unit(kc,ct,lane) = kc*512 + ct*64 + lane, lane=(n&15)+((k>>3)&3)*16, elem j=k&7.
// g=0: KPAD=32 (k>=16 zero), else 128. lo blob at WB+BLOBSZ.
__global__ void preconv_kernel(const float* __restrict__ W1_0, const float* __restrict__ W1,
                               const float* __restrict__ W2, const float* __restrict__ Wr1,
                               ushort_t* __restrict__ WB) {
  int g = blockIdx.y;
  int e = blockIdx.x * 256 + threadIdx.x;
  int KP = (g == 0) ? 32 : 128;
  if (e >= KP * 128) return;
  int k = e >> 7, n = e & 127;
  float v;
  if (g == 0) v = (k < 16) ? W1_0[k * 128 + n] : 0.0f;
  else if (g <= 7) v = W1[(size_t)(g - 1) * 16384 + e];
  else if (g <= 15) v = W2[(size_t)(g - 8) * 16384 + e];
  else v = Wr1[e];
  size_t base = (g == 0) ? 0 : (8192 + (size_t)(g - 1) * 32768);
  int unit = ((k >> 5) << 9) + ((n >> 4) << 6) + (n & 15) + (((k >> 3) & 3) << 4);
  ushort_t h, l;
  bsplit(v, h, l);
  WB[base + (size_t)unit * 8 + (k & 7)] = h;
  WB[BLOBSZ + base + (size_t)unit * 8 + (k & 7)] = l;
}

// ============================ Aggregation ============================

// layer 0: F=16 fp32 in/out
__global__ __launch_bounds__(256) void agg16_kernel(
    const float* __restrict__ X, const int* __restrict__ rp, const int* __restrict__ colb,
    const float* __restrict__ eps, float* __restrict__ Z, int N) {
  int g = threadIdx.x >> 3;
  int l = threadIdx.x & 7;
  int n = blockIdx.x * 32 + g;
  if (n >= N) return;
  float e = 1.0f + eps[0];
  const float2* X2 = (const float2*)X;
  float2 self = X2[(size_t)n * 8 + l];
  float2 acc = make_float2(self.x * e, self.y * e);
  float2 acc2 = make_float2(0.0f, 0.0f);
  int beg = rp[n], end = rp[n + 1];
  int p = beg;
  for (; p + 4 <= end; p += 4) {
    int s0 = colb[p], s1 = colb[p + 1], s2 = colb[p + 2], s3 = colb[p + 3];
    float2 v0 = X2[(size_t)s0 * 8 + l];
    float2 v1 = X2[(size_t)s1 * 8 + l];
    float2 v2 = X2[(size_t)s2 * 8 + l];
    float2 v3 = X2[(size_t)s3 * 8 + l];
    acc.x += v0.x; acc.y += v0.y;
    acc2.x += v1.x; acc2.y += v1.y;
    acc.x += v2.x; acc.y += v2.y;
    acc2.x += v3.x; acc2.y += v3.y;
  }
  for (; p < end; ++p) {
    int s = colb[p];
    float2 v = X2[(size_t)s * 8 + l];
    acc.x += v.x; acc.y += v.y;
  }
  acc.x += acc2.x; acc.y += acc2.y;
  ((float2*)Z)[(size_t)n * 8 + l] = acc;
}

// layers 1..7: fp32 Y, fused h=relu(a*y+c), SKIP += h(self), Z fp32; unroll 8
__global__ __launch_bounds__(256) void agg128_kernel(
    const float* __restrict__ Y, const float* __restrict__ av, const float* __restrict__ cv,
    const int* __restrict__ rp, const int* __restrict__ colb,
    const float* __restrict__ eps, int layer, float* __restrict__ Z,
    float* __restrict__ SKIP, int N) {
  int wv = threadIdx.x >> 6;
  int lane = threadIdx.x & 63;
  int n = blockIdx.x * 4 + wv;
  if (n >= N) return;
  float e = 1.0f + eps[layer];
  float2 a2 = *(const float2*)(av + lane * 2);
  float2 c2 = *(const float2*)(cv + lane * 2);
  const float2* Y2 = (const float2*)Y;
  float2 sv = Y2[(size_t)n * 64 + lane];
  float hx = fmaxf(fmaf(a2.x, sv.x, c2.x), 0.0f);
  float hy = fmaxf(fmaf(a2.y, sv.y, c2.y), 0.0f);
  if (SKIP) {
    float2* S2 = (float2*)SKIP;
    float2 s = S2[(size_t)n * 64 + lane];
    s.x += hx; s.y += hy;
    S2[(size_t)n * 64 + lane] = s;
  }
  float ax = hx * e, ay = hy * e;
  float bx = 0.0f, by = 0.0f, cx = 0.0f, cy = 0.0f, dx = 0.0f, dy = 0.0f;
  int beg = rp[n], end = rp[n + 1];
  int p = beg;
  for (; p + 8 <= end; p += 8) {
    int s0 = colb[p], s1 = colb[p + 1], s2 = colb[p + 2], s3 = colb[p + 3];
    int s4 = colb[p + 4], s5 = colb[p + 5], s6 = colb[p + 6], s7 = colb[p + 7];
    float2 v0 = Y2[(size_t)s0 * 64 + lane];
    float2 v1 = Y2[(size_t)s1 * 64 + lane];
    float2 v2 = Y2[(size_t)s2 * 64 + lane];
    float2 v3 = Y2[(size_t)s3 * 64 + lane];
    float2 v4 = Y2[(size_t)s4 * 64 + lane];
    float2 v5 = Y2[(size_t)s5 * 64 + lane];
    float2 v6 = Y2[(size_t)s6 * 64 + lane];
    float2 v7 = Y2[(size_t)s7 * 64 + lane];
    ax += fmaxf(fmaf(a2.x, v0.x, c2.x), 0.0f);
    ay += fmaxf(fmaf(a2.y, v0.y, c2.y), 0.0f);
    bx += fmaxf(fmaf(a2.x, v1.x, c2.x), 0.0f);
    by += fmaxf(fmaf(a2.y, v1.y, c2.y), 0.0f);
    cx += fmaxf(fmaf(a2.x, v2.x, c2.x), 0.0f);
    cy += fmaxf(fmaf(a2.y, v2.y, c2.y), 0.0f);
    dx += fmaxf(fmaf(a2.x, v3.x, c2.x), 0.0f);
    dy += fmaxf(fmaf(a2.y, v3.y, c2.y), 0.0f);
    ax += fmaxf(fmaf(a2.x, v4.x, c2.x), 0.0f);
    ay += fmaxf(fmaf(a2.y, v4.y, c2.y), 0.0f);
    bx += fmaxf(fmaf(a2.x, v5.x, c2.x), 0.0f);
    by += fmaxf(fmaf(a2.y, v5.y, c2.y), 0.0f);
    cx += fmaxf(fmaf(a2.x, v6.x, c2.x), 0.0f);
    cy += fmaxf(fmaf(a2.y, v6.y, c2.y), 0.0f);
    dx += fmaxf(fmaf(a2.x, v7.x, c2.x), 0.0f);
    dy += fmaxf(fmaf(a2.y, v7.y, c2.y), 0.0f);
  }
  for (; p < end; ++p) {
    int s = colb[p];
    float2 v = Y2[(size_t)s * 64 + lane];
    ax += fmaxf(fmaf(a2.x, v.x, c2.x), 0.0f);
    ay += fmaxf(fmaf(a2.y, v.y, c2.y), 0.0f);
  }
  ax += bx + cx + dx;
  ay += by + cy + dy;
  ((float2*)Z)[(size_t)n * 64 + lane] = make_float2(ax, ay);
}

// ============================ split-bf16 MFMA GEMM + BN stats + fold ============================
// C(fp32)[M,128] = op(A)[M,K] @ B + bias via A_hi*B_hi + A_lo*B_hi + A_hi*B_lo.
// MODE 0: op=A   MODE 1: op=relu(pa*A+pc)   MODE 2: op=0.25*(A + relu(pa*A2+pc))
// MODE 3: A fp32 [M,16], KTOT=32 zero-padded
template <int KTOT, int BK, int MODE>
__global__ __launch_bounds__(256, 3) void gemm_mfma(
    const float* __restrict__ A, const float* __restrict__ A2,
    const ushort_t* __restrict__ Bhi, const ushort_t* __restrict__ Blo,
    const float* __restrict__ bias,
    const float* __restrict__ pa, const float* __restrict__ pc,
    float* __restrict__ C,
    float* __restrict__ gsum, float* __restrict__ gsq,
    float* __restrict__ aout, float* __restrict__ cout, int* __restrict__ cnt,
    const float* __restrict__ gamma, const float* __restrict__ beta,
    float invN, int M, int nb) {
  constexpr int NU = BK / 8;           // 16B units per A row per k0
  constexpr int ASTR = BK + 8;         // A row stride (bf16 elems), keeps 16B align
  __shared__ __align__(16) ushort_t As_hi[128 * ASTR];
  __shared__ __align__(16) ushort_t As_lo[128 * ASTR];
  __shared__ __align__(16) ushort_t Bs_hi[BK * 128];
  __shared__ __align__(16) ushort_t Bs_lo[BK * 128];
  __shared__ float s_sum[128];
  __shared__ float s_sq[128];
  __shared__ int s_last;
  const int tid = threadIdx.x;
  const int w = tid >> 6;
  const int lane = tid & 63;
  const int ln = lane & 15;
  const int quad = lane >> 4;
  const int brow = blockIdx.x * 128;

  f32x4 acc[2][8];
#pragma unroll
  for (int rt = 0; rt < 2; ++rt)
#pragma unroll
    for (int ct = 0; ct < 8; ++ct) acc[rt][ct] = (f32x4){0.0f, 0.0f, 0.0f, 0.0f};

  for (int k0 = 0; k0 < KTOT; k0 += BK) {
    // ---- stage A: read fp32, apply op, split hi/lo ----
    constexpr int AIT = 128 * NU / 256;
#pragma unroll
    for (int it = 0; it < AIT; ++it) {
      int idx = tid + it * 256;
      int row = idx / NU;
      int u = idx % NU;
      int grow = brow + row;
      if (grow >= M) grow = M - 1;
      int gk = k0 + u * 8;
      float v[8];
      if constexpr (MODE == 3) {
        if (gk < 16) {
          float4 a0 = *(const float4*)(A + (size_t)grow * 16 + gk);
          float4 a1 = *(const float4*)(A + (size_t)grow * 16 + gk + 4);
          v[0] = a0.x; v[1] = a0.y; v[2] = a0.z; v[3] = a0.w;
          v[4] = a1.x; v[5] = a1.y; v[6] = a1.z; v[7] = a1.w;
        } else {
#pragma unroll
          for (int j = 0; j < 8; ++j) v[j] = 0.0f;
        }
      } else {
        float4 a0 = *(const float4*)(A + (size_t)grow * KTOT + gk);
        float4 a1 = *(const float4*)(A + (size_t)grow * KTOT + gk + 4);
        v[0] = a0.x; v[1] = a0.y; v[2] = a0.z; v[3] = a0.w;
        v[4] = a1.x; v[5] = a1.y; v[6] = a1.z; v[7] = a1.w;
        if constexpr (MODE == 1) {
          float4 p0 = *(const float4*)(pa + gk);
          float4 p1 = *(const float4*)(pa + gk + 4);
          float4 q0 = *(const float4*)(pc + gk);
          float4 q1 = *(const float4*)(pc + gk + 4);
          float pp[8] = {p0.x, p0.y, p0.z, p0.w, p1.x, p1.y, p1.z, p1.w};
          float qq[8] = {q0.x, q0.y, q0.z, q0.w, q1.x, q1.y, q1.z, q1.w};
#pragma unroll
          for (int j = 0; j < 8; ++j) v[j] = fmaxf(fmaf(pp[j], v[j], qq[j]), 0.0f);
        } else if constexpr (MODE == 2) {
          float4 y0 = *(const float4*)(A2 + (size_t)grow * KTOT + gk);
          float4 y1 = *(const float4*)(A2 + (size_t)grow * KTOT + gk + 4);
          float4 p0 = *(const float4*)(pa + gk);
          float4 p1 = *(const float4*)(pa + gk + 4);
          float4 q0 = *(const float4*)(pc + gk);
          float4 q1 = *(const float4*)(pc + gk + 4);
          float yy[8] = {y0.x, y0.y, y0.z, y0.w, y1.x, y1.y, y1.z, y1.w};
          float pp[8] = {p0.x, p0.y, p0.z, p0.w, p1.x, p1.y, p1.z, p1.w};
          float qq[8] = {q0.x, q0.y, q0.z, q0.w, q1.x, q1.y, q1.z, q1.w};
#pragma unroll
          for (int j = 0; j < 8; ++j)
            v[j] = 0.25f * (v[j] + fmaxf(fmaf(pp[j], yy[j], qq[j]), 0.0f));
        }
      }
      uint4 ohi, olo;
      {
        ushort_t h[8], l[8];
#pragma unroll
        for (int j = 0; j < 8; ++j) bsplit(v[j], h[j], l[j]);
        ohi.x = (uint_t)h[0] | ((uint_t)h[1] << 16);
        ohi.y = (uint_t)h[2] | ((uint_t)h[3] << 16);
        ohi.z = (uint_t)h[4] | ((uint_t)h[5] << 16);
        ohi.w = (uint_t)h[6] | ((uint_t)h[7] << 16);
        olo.x = (uint_t)l[0] | ((uint_t)l[1] << 16);
        olo.y = (uint_t)l[2] | ((uint_t)l[3] << 16);
        olo.z = (uint_t)l[4] | ((uint_t)l[5] << 16);
        olo.w = (uint_t)l[6] | ((uint_t)l[7] << 16);
      }
      int off = row * ASTR + ((u ^ (row & (NU - 1))) << 3);
      *(uint4*)&As_hi[off] = ohi;
      *(uint4*)&As_lo[off] = olo;
    }
    // ---- stage B hi/lo (contiguous frag-ordered copy) ----
    constexpr int BIT = BK * 16 / 256;
#pragma unroll
    for (int it = 0; it < BIT; ++it) {
      int idx = tid + it * 256;
      *(uint4*)&Bs_hi[idx << 3] = *(const uint4*)(Bhi + (size_t)k0 * 128 + ((size_t)idx << 3));
      *(uint4*)&Bs_lo[idx << 3] = *(const uint4*)(Blo + (size_t)k0 * 128 + ((size_t)idx << 3));
    }
    __syncthreads();
    // ---- MFMA: 3-term split product ----
#pragma unroll
    for (int kcl = 0; kcl < BK / 32; ++kcl) {
      int u = kcl * 4 + quad;
      int r0 = (w << 5) + ln;
      int r1 = r0 + 16;
      short8 a0h = *(const short8*)&As_hi[r0 * ASTR + ((u ^ (r0 & (NU - 1))) << 3)];
      short8 a0l = *(const short8*)&As_lo[r0 * ASTR + ((u ^ (r0 & (NU - 1))) << 3)];
      short8 a1h = *(const short8*)&As_hi[r1 * ASTR + ((u ^ (r1 & (NU - 1))) << 3)];
      short8 a1l = *(const short8*)&As_lo[r1 * ASTR + ((u ^ (r1 & (NU - 1))) << 3)];
#pragma unroll
      for (int ct = 0; ct < 8; ++ct) {
        int bo = ((((kcl << 3) + ct) << 6) + lane) << 3;
        short8 bh = *(const short8*)&Bs_hi[bo];
        short8 bl = *(const short8*)&Bs_lo[bo];
        acc[0][ct] = __builtin_amdgcn_mfma_f32_16x16x32_bf16(a0h, bh, acc[0][ct], 0, 0, 0);
        acc[0][ct] = __builtin_amdgcn_mfma_f32_16x16x32_bf16(a0l, bh, acc[0][ct], 0, 0, 0);
        acc[0][ct] = __builtin_amdgcn_mfma_f32_16x16x32_bf16(a0h, bl, acc[0][ct], 0, 0, 0);
        acc[1][ct] = __builtin_amdgcn_mfma_f32_16x16x32_bf16(a1h, bh, acc[1][ct], 0, 0, 0);
        acc[1][ct] = __builtin_amdgcn_mfma_f32_16x16x32_bf16(a1l, bh, acc[1][ct], 0, 0, 0);
        acc[1][ct] = __builtin_amdgcn_mfma_f32_16x16x32_bf16(a1h, bl, acc[1][ct], 0, 0, 0);
      }
    }
    __syncthreads();
  }

  // ---- epilogue: bias, stats, fp32 store ----
  if (tid < 128) { s_sum[tid] = 0.0f; s_sq[tid] = 0.0f; }
  __syncthreads();
#pragma unroll
  for (int ct = 0; ct < 8; ++ct) {
    int col = (ct << 4) + ln;
    float bsc = bias[col];
    float csum = 0.0f, csq = 0.0f;
#pragma unroll
    for (int rt = 0; rt < 2; ++rt) {
#pragma unroll
      for (int i = 0; i < 4; ++i) {
        int row = brow + (w << 5) + (rt << 4) + (quad << 2) + i;
        if (row < M) {
          float y = acc[rt][ct][i] + bsc;
          csum += y; csq += y * y;
          C[(size_t)row * 128 + col] = y;
        }
      }
    }
    atomicAdd(&s_sum[col], csum);
    atomicAdd(&s_sq[col], csq);
  }
  __syncthreads();
  if (tid < 128) {
    atomicAdd(&gsum[tid], s_sum[tid]);
    atomicAdd(&gsq[tid], s_sq[tid]);
  }
  if (tid == 0) {
    __threadfence();
    int v = __hip_atomic_fetch_add(cnt, 1, __ATOMIC_ACQ_REL, __HIP_MEMORY_SCOPE_AGENT);
    s_last = (v == nb - 1) ? 1 : 0;
  }
  __syncthreads();
  if (s_last && tid < 128) {
    float s = __hip_atomic_load(&gsum[tid], __ATOMIC_RELAXED, __HIP_MEMORY_SCOPE_AGENT);
    float q = __hip_atomic_load(&gsq[tid], __ATOMIC_RELAXED, __HIP_MEMORY_SCOPE_AGENT);
    float mu = s * invN;
    float var = q * invN - mu * mu;
    float sc = gamma[tid] * rsqrtf(var + BN_EPS);
    aout[tid] = sc;
    cout[tid] = beta[tid] - sc * mu;
  }
}

// ============================ regressor head ============================
__global__ __launch_bounds__(256) void finaldot_kernel(
    const float* __restrict__ Y, const float* __restrict__ a, const float* __restrict__ c,
    const float* __restrict__ Wr2, const float* __restrict__ br2,
    float* __restrict__ out, int N) {
  int wv = threadIdx.x >> 6;
  int lane = threadIdx.x & 63;
  int n = blockIdx.x * 4 + wv;
  if (n >= N) return;
  float2 y = *(const float2*)(Y + (size_t)n * HID + lane * 2);
  int c0 = lane * 2;
  float s = fmaxf(fmaf(a[c0], y.x, c[c0]), 0.0f) * Wr2[c0] +
            fmaxf(fmaf(a[c0 + 1], y.y, c[c0 + 1]), 0.0f) * Wr2[c0 + 1];
  for (int off = 32; off > 0; off >>= 1) s += __shfl_down(s, off, 64);
  if (lane == 0) out[n] = 1.0f / (1.0f + expf(-(s + br2[0])));
}

// ============================ launch ============================
extern "C" void kernel_launch(void* const* d_in, const int* in_sizes, int n_in,
                              void* d_out, int out_size, void* d_ws, size_t ws_size,
                              hipStream_t stream) {
  const float* x     = (const float*)d_in[0];
  const int*   ei    = (const int*)d_in[1];
  const float* eps   = (const float*)d_in[2];
  const float* W1_0  = (const float*)d_in[3];
  const float* b1_0  = (const float*)d_in[4];
  const float* W1    = (const float*)d_in[5];
  const float* b1    = (const float*)d_in[6];
  const float* g_in  = (const float*)d_in[7];
  const float* be_in = (const float*)d_in[8];
  const float* W2    = (const float*)d_in[9];
  const float* b2    = (const float*)d_in[10];
  const float* g_out = (const float*)d_in[11];
  const float* be_out= (const float*)d_in[12];
  const float* Wr1   = (const float*)d_in[13];
  const float* br1   = (const float*)d_in[14];
  const float* gr    = (const float*)d_in[15];
  const float* ber   = (const float*)d_in[16];
  const float* Wr2   = (const float*)d_in[17];
  const float* br2   = (const float*)d_in[18];
  float* out = (float*)d_out;

  const int N = in_sizes[0] / IN_F;   // 100000
  const int E = in_sizes[1] / 2;      // 1600000
  const int* srcv = ei;
  const int* dstv = ei + E;

  // workspace carve: 2 activation buffers (in-place GEMM is per-block row-local)
  float* X0   = (float*)d_ws;                  // [N][128] fp32
  float* X1   = X0 + (size_t)N * HID;
  float* SKIP = X1 + (size_t)N * HID;
  int* colb    = (int*)(SKIP + (size_t)N * HID);
  int* row_ptr = colb + E;
  int* deg     = row_ptr + (N + 4);
  int* cursor  = deg + N;
  int* bsum    = cursor + N;
  int* boff    = bsum + 256;
  float* arena = (float*)(boff + 256);         // 17 slots x 640 floats
  ushort_t* WB = (ushort_t*)(arena + 17 * 640);// hi blob | lo blob (2*BLOBSZ ushorts)

  hipMemsetAsync(deg, 0, sizeof(int) * N, stream);
  hipMemsetAsync(SKIP, 0, sizeof(float) * (size_t)N * HID, stream);
  hipMemsetAsync(arena, 0, sizeof(float) * 17 * 640, stream);

  // CSR build
  hist_kernel<<<(E + 255) / 256, 256, 0, stream>>>(dstv, deg, E);
  int nbs = (N + 1023) / 1024;
  scan1_kernel<<<nbs, 256, 0, stream>>>(deg, bsum, N);
  scan2_kernel<<<1, 256, 0, stream>>>(bsum, boff, nbs, row_ptr, N, E);
  scan3_kernel<<<nbs, 256, 0, stream>>>(deg, boff, row_ptr, cursor, N);
  fill_kernel<<<(E + 255) / 256, 256, 0, stream>>>(srcv, dstv, cursor, colb, E);
  preconv_kernel<<<dim3(64, 17), 256, 0, stream>>>(W1_0, W1, W2, Wr1, WB);

  const int gg = (N + 127) / 128;
  const float invN = 1.0f / (float)N;
#define SLOT(s) (arena + (s) * 640)
#define SSUM(s) SLOT(s)
#define SSQ(s)  (SLOT(s) + 128)
#define SA(s)   (SLOT(s) + 256)
#define SC(s)   (SLOT(s) + 384)
#define SCNT(s) ((int*)(SLOT(s) + 512))
#define WBH(g)  (WB + ((g) == 0 ? 0 : (8192 + (size_t)((g) - 1) * 32768)))
#define WBL(g)  (WBH(g) + BLOBSZ)

  // ---- layer 0 ----  (agg16: x -> X0[N,16]; g0a: X0 -> X1; g0b: X1 -> X1 in-place)
  agg16_kernel<<<(N + 31) / 32, 256, 0, stream>>>(x, row_ptr, colb, eps, X0, N);
  gemm_mfma<32, 32, 3><<<gg, 256, 0, stream>>>(
      X0, nullptr, WBH(0), WBL(0), b1_0, nullptr, nullptr, X1,
      SSUM(0), SSQ(0), SA(0), SC(0), SCNT(0), g_in, be_in, invN, N, gg);
  gemm_mfma<128, 32, 1><<<gg, 256, 0, stream>>>(
      X1, nullptr, WBH(8), WBL(8), b2, SA(0), SC(0), X1,
      SSUM(1), SSQ(1), SA(1), SC(1), SCNT(1), g_out, be_out, invN, N, gg);
  // Y0 in X1

  // ---- layers 1..7 ----  agg: X1->X0; gemm1: X0->X0; gemm2: X0->X1
  for (int L = 1; L < NLAYERS; ++L) {
    int sp = 2 * L - 1;
    int s0 = 2 * L, s1 = 2 * L + 1;
    float* skipw = ((L - 1) & 1) ? SKIP : nullptr;  // fold h_{L-1} at L=2,4,6
    agg128_kernel<<<(N + 3) / 4, 256, 0, stream>>>(
        X1, SA(sp), SC(sp), row_ptr, colb, eps, L, X0, skipw, N);
    gemm_mfma<128, 32, 0><<<gg, 256, 0, stream>>>(
        X0, nullptr, WBH(L), WBL(L), b1 + (size_t)(L - 1) * HID, nullptr, nullptr, X0,
        SSUM(s0), SSQ(s0), SA(s0), SC(s0), SCNT(s0),
        g_in + (size_t)L * HID, be_in + (size_t)L * HID, invN, N, gg);
    gemm_mfma<128, 32, 1><<<gg, 256, 0, stream>>>(
        X0, nullptr, WBH(8 + L), WBL(8 + L), b2 + (size_t)L * HID, SA(s0), SC(s0), X1,
        SSUM(s1), SSQ(s1), SA(s1), SC(s1), SCNT(s1),
        g_out + (size_t)L * HID, be_out + (size_t)L * HID, invN, N, gg);
  }
  // Y7 in X1, slot 15 holds its outer-BN params

  // ---- regressor: op = 0.25*(SKIP + relu(a7*Y7+c7)) ----
  gemm_mfma<128, 32, 2><<<gg, 256, 0, stream>>>(
      SKIP, X1, WBH(16), WBL(16), br1, SA(15), SC(15), X0,
      SSUM(16), SSQ(16), SA(16), SC(16), SCNT(16), gr, ber, invN, N, gg);
  finaldot_kernel<<<(N + 3) / 4, 256, 0, stream>>>(X0, SA(16), SC(16), Wr2, br2, out, N);
#undef SLOT
#undef SSUM
#undef SSQ
#undef SA
#undef SC
#undef SCNT
#undef WBH
#undef WBL
}